// Round 1
// baseline (960.490 us; speedup 1.0000x reference)
//
#include <hip/hip_runtime.h>
#include <hip/hip_bf16.h>
#include <math.h>

// Problem constants
#define BB 128
#define SS 512
#define NN 32
#define DD 512
#define HH 2
#define MM (BB * NN)          // 4096 rows of the node matrix
#define DSQ (DD * DD)         // 262144

// ---------------------------------------------------------------------------
// 1. Adjacency build: g_gt/g_lt [B,32,32], row-normalized
// ---------------------------------------------------------------------------
__global__ __launch_bounds__(256) void adj_k(const int* __restrict__ order,
                                             float* __restrict__ g_gt,
                                             float* __restrict__ g_lt) {
    int b = blockIdx.x;
    __shared__ int ord[NN];
    __shared__ float sgt[NN][NN + 1];
    __shared__ float slt[NN][NN + 1];
    __shared__ float rs_gt[NN], rs_lt[NN];
    int tid = threadIdx.x;
    if (tid < NN) ord[tid] = order[b * NN + tid];
    __syncthreads();
    for (int q = 0; q < 4; ++q) {
        int idx = tid + 256 * q;
        int n = idx >> 5, m = idx & 31;
        bool valid = (ord[n] > 0) && (ord[m] > 0) && (n != m);
        float eye = (n == m) ? 1.f : 0.f;
        bool gt = ord[n] > ord[m];
        sgt[n][m] = ((valid && gt) ? 1.f : 0.f) + eye;
        slt[n][m] = ((valid && !gt) ? 1.f : 0.f) + eye;
    }
    __syncthreads();
    if (tid < NN) {
        float s1 = 0.f, s2 = 0.f;
        for (int m = 0; m < NN; ++m) { s1 += sgt[tid][m]; s2 += slt[tid][m]; }
        rs_gt[tid] = s1; rs_lt[tid] = s2;
    }
    __syncthreads();
    for (int q = 0; q < 4; ++q) {
        int idx = tid + 256 * q;
        int n = idx >> 5, m = idx & 31;
        g_gt[b * 1024 + idx] = sgt[n][m] / rs_gt[n];
        g_lt[b * 1024 + idx] = slt[n][m] / rs_lt[n];
    }
}

// ---------------------------------------------------------------------------
// 2. Scatter map: slot[b][s] = node index n with pos[b,n]==s, else -1
// ---------------------------------------------------------------------------
__global__ void slot_init_k(int* __restrict__ slot) {
    int i = blockIdx.x * 256 + threadIdx.x;
    if (i < BB * SS) slot[i] = -1;
}

__global__ void slot_scatter_k(const int* __restrict__ pos, int* __restrict__ slot) {
    int i = blockIdx.x * 256 + threadIdx.x;  // over B*N
    if (i < BB * NN) {
        int p = pos[i];
        if (p >= 0) slot[(i >> 5) * SS + p] = (i & 31);
    }
}

// ---------------------------------------------------------------------------
// 3. Precombine gate weights:
//    wg1 = Wg[0:D] + Wg[2D:3D] + Wg[3D:4D]; wg2 = Wg[D:2D] + Wg[2D:3D] - Wg[3D:4D]
// ---------------------------------------------------------------------------
__global__ void combine_wg_k(const float* __restrict__ w_g,
                             float* __restrict__ wg1, float* __restrict__ wg2) {
    int idx = blockIdx.x * 256 + threadIdx.x;  // over H*D*D
    if (idx >= HH * DSQ) return;
    int h = idx / DSQ;
    int rem = idx - h * DSQ;
    int d = rem / DD, e = rem - d * DD;
    const float* base = w_g + (size_t)h * 4 * DSQ;
    float a  = base[(size_t)d * DD + e];
    float b2 = base[(size_t)(DD + d) * DD + e];
    float c  = base[(size_t)(2 * DD + d) * DD + e];
    float d4 = base[(size_t)(3 * DD + d) * DD + e];
    wg1[idx] = a + c + d4;
    wg2[idx] = b2 + c - d4;
}

// ---------------------------------------------------------------------------
// 4. Batched small matmul: out[b,n,d] = sum_m g[b,n,m] * x[b,m,d]
//    grid (B, D/32), block 256
// ---------------------------------------------------------------------------
__global__ __launch_bounds__(256) void gmul_k(const float* __restrict__ g,
                                              const float* __restrict__ x,
                                              float* __restrict__ out) {
    int b = blockIdx.x;
    int d0 = blockIdx.y * 32;
    __shared__ float gs[NN][NN + 1];
    __shared__ float xs[NN][NN];
    int tid = threadIdx.x;
    int dl = tid & 31;
    int mbase = tid >> 5;  // 0..7
    for (int q = 0; q < 4; ++q) {
        int idx = tid + 256 * q;
        gs[idx >> 5][idx & 31] = g[b * 1024 + idx];
    }
    for (int q = 0; q < 4; ++q) {
        int m = mbase + 8 * q;
        xs[m][dl] = x[((size_t)b * NN + m) * DD + d0 + dl];
    }
    __syncthreads();
    for (int q = 0; q < 4; ++q) {
        int n = mbase + 8 * q;
        float acc = 0.f;
#pragma unroll
        for (int m = 0; m < NN; ++m) acc += gs[n][m] * xs[m][dl];
        out[((size_t)b * NN + n) * DD + d0 + dl] = acc;
    }
}

// ---------------------------------------------------------------------------
// 5. Fused GEMM: out = epilogue(A1@W1 (+ A2@W2) + bias)
//    A: [M,512], W: [512,512].  64x64 tile, BK=16, 256 threads, 4x4/thread.
//    GATE: g=sigmoid(acc); out = g*gin1 + (1-g)*gin2.  else: relu.
// ---------------------------------------------------------------------------
template <bool DUAL, bool GATE>
__global__ __launch_bounds__(256) void gemm_k(const float* __restrict__ A1,
                                              const float* __restrict__ W1,
                                              const float* __restrict__ A2,
                                              const float* __restrict__ W2,
                                              const float* __restrict__ bias,
                                              const float* __restrict__ gin1,
                                              const float* __restrict__ gin2,
                                              float* __restrict__ out) {
    __shared__ __align__(16) float As[16][68];  // k-major (transposed A tile)
    __shared__ __align__(16) float Bs[16][68];
    int tid = threadIdx.x;
    int tx = tid & 15, ty = tid >> 4;
    int bm = blockIdx.x * 64;
    int bn = blockIdx.y * 64;
    float c[4][4] = {};

    int ar = tid >> 2;         // 0..63 : row within A tile
    int ac = (tid & 3) * 4;    // 0,4,8,12 : k within A tile
    int br = tid >> 4;         // 0..15 : k within W tile
    int bc = (tid & 15) * 4;   // 0..60 : col within W tile

    const int nsrc = DUAL ? 2 : 1;
    for (int src = 0; src < nsrc; ++src) {
        const float* A = src ? A2 : A1;
        const float* W = src ? W2 : W1;
        for (int k0 = 0; k0 < DD; k0 += 16) {
            float4 av = *(const float4*)(A + (size_t)(bm + ar) * DD + k0 + ac);
            float4 wv = *(const float4*)(W + (size_t)(k0 + br) * DD + bn + bc);
            __syncthreads();
            As[ac + 0][ar] = av.x;
            As[ac + 1][ar] = av.y;
            As[ac + 2][ar] = av.z;
            As[ac + 3][ar] = av.w;
            *(float4*)&Bs[br][bc] = wv;
            __syncthreads();
#pragma unroll
            for (int kk = 0; kk < 16; ++kk) {
                float4 a4 = *(const float4*)&As[kk][ty * 4];
                float4 b4 = *(const float4*)&Bs[kk][tx * 4];
                float a[4] = {a4.x, a4.y, a4.z, a4.w};
                float b[4] = {b4.x, b4.y, b4.z, b4.w};
#pragma unroll
                for (int i = 0; i < 4; ++i)
#pragma unroll
                    for (int j = 0; j < 4; ++j) c[i][j] += a[i] * b[j];
            }
        }
    }
#pragma unroll
    for (int i = 0; i < 4; ++i) {
        int row = bm + ty * 4 + i;
#pragma unroll
        for (int j = 0; j < 4; ++j) {
            int col = bn + tx * 4 + j;
            float v = c[i][j] + bias[col];
            size_t idx = (size_t)row * DD + col;
            if (GATE) {
                float g = 1.f / (1.f + expf(-v));
                out[idx] = g * gin1[idx] + (1.f - g) * gin2[idx];
            } else {
                out[idx] = fmaxf(v, 0.f);
            }
        }
    }
}

// ---------------------------------------------------------------------------
// 6. gnn_info write + partial max:  grid (B, 16), block 256 (2 d per thread)
// ---------------------------------------------------------------------------
__global__ __launch_bounds__(256) void gnn_k(const float* __restrict__ enc,
                                             const float* __restrict__ node,
                                             const int* __restrict__ slot,
                                             float* __restrict__ out_gnn,
                                             float* __restrict__ partial) {
    int b = blockIdx.x;
    int s0 = blockIdx.y * 32;
    int t = threadIdx.x;
    float mx0 = -INFINITY, mx1 = -INFINITY;
    for (int s = s0; s < s0 + 32; ++s) {
        int n = slot[b * SS + s];
        size_t ebase = ((size_t)s * BB + b) * DD;
        float a0 = 0.f, a1 = 0.f;
        if (n >= 0) {
            size_t nbase = ((size_t)b * NN + n) * DD;
            a0 = node[nbase + t];
            a1 = node[nbase + t + 256];
        }
        float v0 = enc[ebase + t] + a0;
        float v1 = enc[ebase + t + 256] + a1;
        out_gnn[ebase + t] = v0;
        out_gnn[ebase + t + 256] = v1;
        mx0 = fmaxf(mx0, v0);
        mx1 = fmaxf(mx1, v1);
    }
    size_t pbase = ((size_t)b * 16 + blockIdx.y) * DD;
    partial[pbase + t] = mx0;
    partial[pbase + t + 256] = mx1;
}

__global__ void pmax_k(const float* __restrict__ partial, float* __restrict__ out_prob) {
    int i = blockIdx.x * 256 + threadIdx.x;  // over B*D
    if (i >= BB * DD) return;
    int b = i >> 9, d = i & 511;
    float m = -INFINITY;
    for (int c = 0; c < 16; ++c) m = fmaxf(m, partial[((size_t)b * 16 + c) * DD + d]);
    out_prob[i] = m;
}

__global__ void nemb_k(const float* __restrict__ num_enc, const float* __restrict__ node,
                       float* __restrict__ out) {
    size_t i = (size_t)blockIdx.x * 256 + threadIdx.x;  // over B*N*D
    out[i] = num_enc[i] + node[i];
}

// ---------------------------------------------------------------------------
// Host launch
// ---------------------------------------------------------------------------
extern "C" void kernel_launch(void* const* d_in, const int* in_sizes, int n_in,
                              void* d_out, int out_size, void* d_ws, size_t ws_size,
                              hipStream_t stream) {
    const float* enc     = (const float*)d_in[0];   // [S,B,D]
    const float* num_enc = (const float*)d_in[1];   // [B,N,D]
    const int*   pos     = (const int*)d_in[2];     // [B,N]
    const int*   order   = (const int*)d_in[3];     // [B,N]
    const float* w_n1a = (const float*)d_in[4];  const float* b_n1a = (const float*)d_in[5];
    const float* w_n1b = (const float*)d_in[6];  const float* b_n1b = (const float*)d_in[7];
    const float* w_n2a = (const float*)d_in[8];  const float* b_n2a = (const float*)d_in[9];
    const float* w_n2b = (const float*)d_in[10]; const float* b_n2b = (const float*)d_in[11];
    const float* w_g   = (const float*)d_in[12]; const float* b_g   = (const float*)d_in[13];
    const float* w_o   = (const float*)d_in[14]; const float* b_o   = (const float*)d_in[15];

    // Workspace layout (floats)
    float* ws = (float*)d_ws;
    float* g_gt   = ws;                       // 131072
    float* g_lt   = g_gt + BB * NN * NN;      // 131072
    int*   slot   = (int*)(g_lt + BB * NN * NN);       // 65536 ints
    float* wg1    = (float*)(slot + BB * SS);          // H*D*D
    float* wg2    = wg1 + HH * DSQ;                    // H*D*D
    float* nodeA  = wg2 + HH * DSQ;                    // M*D
    float* nodeB  = nodeA + (size_t)MM * DD;
    float* ni1    = nodeB + (size_t)MM * DD;
    float* ni2    = ni1 + (size_t)MM * DD;
    float* tmp    = ni2 + (size_t)MM * DD;
    float* partial= tmp + (size_t)MM * DD;             // B*16*D

    float* out_gnn  = (float*)d_out;                        // S*B*D
    float* out_nemb = out_gnn + (size_t)SS * BB * DD;       // B*N*D
    float* out_prob = out_nemb + (size_t)BB * NN * DD;      // B*D

    // Setup
    adj_k<<<BB, 256, 0, stream>>>(order, g_gt, g_lt);
    slot_init_k<<<(BB * SS + 255) / 256, 256, 0, stream>>>(slot);
    slot_scatter_k<<<(BB * NN + 255) / 256, 256, 0, stream>>>(pos, slot);
    combine_wg_k<<<(HH * DSQ + 255) / 256, 256, 0, stream>>>(w_g, wg1, wg2);

    dim3 ggrid(BB, 16);
    dim3 mgrid(MM / 64, DD / 64);

    const float* nodeIn = num_enc;
    for (int h = 0; h < HH; ++h) {
        float* nodeOut = (h == 0) ? nodeA : nodeB;
        // ni1 = relu(gmul(g_gt, node) @ w_n1a + b); ni1 = relu(gmul(g_gt, ni1) @ w_n1b + b)
        gmul_k<<<ggrid, 256, 0, stream>>>(g_gt, nodeIn, tmp);
        gemm_k<false, false><<<mgrid, 256, 0, stream>>>(tmp, w_n1a + h * DSQ, nullptr, nullptr,
                                                        b_n1a + h * DD, nullptr, nullptr, ni1);
        gmul_k<<<ggrid, 256, 0, stream>>>(g_gt, ni1, tmp);
        gemm_k<false, false><<<mgrid, 256, 0, stream>>>(tmp, w_n1b + h * DSQ, nullptr, nullptr,
                                                        b_n1b + h * DD, nullptr, nullptr, ni1);
        // ni2 path with g_lt
        gmul_k<<<ggrid, 256, 0, stream>>>(g_lt, nodeIn, tmp);
        gemm_k<false, false><<<mgrid, 256, 0, stream>>>(tmp, w_n2a + h * DSQ, nullptr, nullptr,
                                                        b_n2a + h * DD, nullptr, nullptr, ni2);
        gmul_k<<<ggrid, 256, 0, stream>>>(g_lt, ni2, tmp);
        gemm_k<false, false><<<mgrid, 256, 0, stream>>>(tmp, w_n2b + h * DSQ, nullptr, nullptr,
                                                        b_n2b + h * DD, nullptr, nullptr, ni2);
        // node_info = gate*ni1 + (1-gate)*ni2, gate = sigmoid(ni1@wg1 + ni2@wg2 + b_g)
        gemm_k<true, true><<<mgrid, 256, 0, stream>>>(ni1, wg1 + h * DSQ, ni2, wg2 + h * DSQ,
                                                      b_g + h * DD, ni1, ni2, tmp);
        // node = relu(node@Wo_a + node_info@Wo_b + b_o)
        gemm_k<true, false><<<mgrid, 256, 0, stream>>>(nodeIn, w_o + (size_t)h * 2 * DSQ, tmp,
                                                       w_o + (size_t)h * 2 * DSQ + DSQ,
                                                       b_o + h * DD, nullptr, nullptr, nodeOut);
        nodeIn = nodeOut;
    }
    const float* nodeF = nodeIn;  // nodeB after 2 hops

    // Outputs
    gnn_k<<<dim3(BB, 16), 256, 0, stream>>>(enc, nodeF, slot, out_gnn, partial);
    pmax_k<<<(BB * DD + 255) / 256, 256, 0, stream>>>(partial, out_prob);
    nemb_k<<<(BB * NN * DD) / 256, 256, 0, stream>>>(num_enc, nodeF, out_nemb);
}

// Round 2
// 522.079 us; speedup vs baseline: 1.8397x; 1.8397x over previous
//
#include <hip/hip_runtime.h>
#include <math.h>

// Problem constants
#define BB 128
#define SS 512
#define NN 32
#define DD 512
#define HH 2
#define MM (BB * NN)          // 4096 rows
#define DSQ (DD * DD)         // 262144

typedef short bf16x8 __attribute__((ext_vector_type(8)));
typedef float f32x4 __attribute__((ext_vector_type(4)));
typedef unsigned short us8 __attribute__((ext_vector_type(8)));

__device__ __forceinline__ unsigned short f2bf(float f) {
    unsigned int u = __float_as_uint(f);
    u += 0x7fffu + ((u >> 16) & 1u);
    return (unsigned short)(u >> 16);
}
__device__ __forceinline__ float bf2f(unsigned short h) {
    return __uint_as_float(((unsigned int)h) << 16);
}
__device__ __forceinline__ void g2l16(const void* gp, void* lp) {
    __builtin_amdgcn_global_load_lds(
        (const __attribute__((address_space(1))) void*)gp,
        (__attribute__((address_space(3))) void*)lp, 16, 0, 0);
}

// ---------------------------------------------------------------------------
// Adjacency build: g_gt/g_lt [B,32,32], row-normalized (fp32)
// ---------------------------------------------------------------------------
__global__ __launch_bounds__(256) void adj_k(const int* __restrict__ order,
                                             float* __restrict__ g_gt,
                                             float* __restrict__ g_lt) {
    int b = blockIdx.x;
    __shared__ int ord[NN];
    __shared__ float sgt[NN][NN + 1];
    __shared__ float slt[NN][NN + 1];
    __shared__ float rs_gt[NN], rs_lt[NN];
    int tid = threadIdx.x;
    if (tid < NN) ord[tid] = order[b * NN + tid];
    __syncthreads();
    for (int q = 0; q < 4; ++q) {
        int idx = tid + 256 * q;
        int n = idx >> 5, m = idx & 31;
        bool valid = (ord[n] > 0) && (ord[m] > 0) && (n != m);
        float eye = (n == m) ? 1.f : 0.f;
        bool gt = ord[n] > ord[m];
        sgt[n][m] = ((valid && gt) ? 1.f : 0.f) + eye;
        slt[n][m] = ((valid && !gt) ? 1.f : 0.f) + eye;
    }
    __syncthreads();
    if (tid < NN) {
        float s1 = 0.f, s2 = 0.f;
        for (int m = 0; m < NN; ++m) { s1 += sgt[tid][m]; s2 += slt[tid][m]; }
        rs_gt[tid] = s1; rs_lt[tid] = s2;
    }
    __syncthreads();
    for (int q = 0; q < 4; ++q) {
        int idx = tid + 256 * q;
        int n = idx >> 5, m = idx & 31;
        g_gt[b * 1024 + idx] = sgt[n][m] / rs_gt[n];
        g_lt[b * 1024 + idx] = slt[n][m] / rs_lt[n];
    }
}

// ---------------------------------------------------------------------------
// Scatter map
// ---------------------------------------------------------------------------
__global__ void slot_init_k(int* __restrict__ slot) {
    int i = blockIdx.x * 256 + threadIdx.x;
    if (i < BB * SS) slot[i] = -1;
}
__global__ void slot_scatter_k(const int* __restrict__ pos, int* __restrict__ slot) {
    int i = blockIdx.x * 256 + threadIdx.x;
    if (i < BB * NN) {
        int p = pos[i];
        if (p >= 0) slot[(i >> 5) * SS + p] = (i & 31);
    }
}

// ---------------------------------------------------------------------------
// Weight prep: transpose + convert to bf16 [n][k] into slot layout
// ---------------------------------------------------------------------------
struct WS { const float* s[12]; int slot[12]; };

__global__ __launch_bounds__(256) void wprep_k(WS w, unsigned short* __restrict__ Wt) {
    int which = blockIdx.x;
    const float* src = w.s[which];
    unsigned short* dst = Wt + (size_t)w.slot[which] * DSQ;
    int tile = blockIdx.y;
    int tr = (tile >> 3) * 64, tc = (tile & 7) * 64;
    __shared__ float sT[64][65];
    int lc = threadIdx.x & 63, g4 = threadIdx.x >> 6;
    for (int i = 0; i < 16; ++i) {
        int lr = g4 * 16 + i;
        sT[lr][lc] = src[(size_t)(tr + lr) * DD + tc + lc];
    }
    __syncthreads();
    for (int i = 0; i < 16; ++i) {
        int lr = g4 * 16 + i;
        dst[(size_t)(tc + lr) * DD + tr + lc] = f2bf(sT[lc][lr]);
    }
}

// combine gate weights + transpose + bf16: slots h*8+4 (wg1t), h*8+5 (wg2t)
__global__ __launch_bounds__(256) void cwg_k(const float* __restrict__ w_g,
                                             unsigned short* __restrict__ Wt) {
    int h = blockIdx.x;
    int tile = blockIdx.y;
    int tr = (tile >> 3) * 64, tc = (tile & 7) * 64;   // tr: k, tc: n
    __shared__ float c1[64][65], c2[64][65];
    const float* base = w_g + (size_t)h * 4 * DSQ;
    int lc = threadIdx.x & 63, g4 = threadIdx.x >> 6;
    for (int i = 0; i < 16; ++i) {
        int lr = g4 * 16 + i;
        int k = tr + lr, n = tc + lc;
        float a  = base[(size_t)k * DD + n];
        float b2 = base[(size_t)(DD + k) * DD + n];
        float c  = base[(size_t)(2 * DD + k) * DD + n];
        float d4 = base[(size_t)(3 * DD + k) * DD + n];
        c1[lr][lc] = a + c + d4;
        c2[lr][lc] = b2 + c - d4;
    }
    __syncthreads();
    unsigned short* d1 = Wt + (size_t)(h * 8 + 4) * DSQ;
    unsigned short* d2 = Wt + (size_t)(h * 8 + 5) * DSQ;
    for (int i = 0; i < 16; ++i) {
        int lr = g4 * 16 + i;
        d1[(size_t)(tc + lr) * DD + tr + lc] = f2bf(c1[lc][lr]);
        d2[(size_t)(tc + lr) * DD + tr + lc] = f2bf(c2[lc][lr]);
    }
}

// fp32 -> bf16 conversion (num_enc -> node0)
__global__ void conv_k(const float* __restrict__ x, unsigned short* __restrict__ o) {
    size_t i = ((size_t)blockIdx.x * 256 + threadIdx.x) * 4;
    float4 v = *(const float4*)(x + i);
    ushort4 r;
    r.x = f2bf(v.x); r.y = f2bf(v.y); r.z = f2bf(v.z); r.w = f2bf(v.w);
    *(ushort4*)(o + i) = r;
}

// ---------------------------------------------------------------------------
// gmul: out[b,n,:] = sum_m g[b,n,m]*x[b,m,:]  (bf16 in/out, fp32 accum)
// grid (B, 4, 2) block 256; each block does 128 d-cols, all 32 n
// ---------------------------------------------------------------------------
struct GM { const float* g; const unsigned short* x; unsigned short* out; };

__global__ __launch_bounds__(256) void gmul_k(GM m0, GM m1) {
    GM m = blockIdx.z ? m1 : m0;
    int b = blockIdx.x;
    int d0 = blockIdx.y * 128;
    __shared__ float gs[NN][NN + 1];
    __shared__ __align__(16) unsigned short xs[NN][128];
    int tid = threadIdx.x;
    for (int q = 0; q < 4; ++q) {
        int idx = tid + 256 * q;
        gs[idx >> 5][idx & 31] = m.g[b * 1024 + idx];
    }
    for (int t = 0; t < 2; ++t) {
        int c = tid + t * 256;       // 512 chunks of 16B
        int row = c >> 4, seg = c & 15;
        *(uint4*)&xs[row][seg * 8] =
            *(const uint4*)(m.x + (size_t)(b * NN + row) * DD + d0 + seg * 8);
    }
    __syncthreads();
    int dl = tid & 15, n0 = tid >> 4;
    for (int t = 0; t < 2; ++t) {
        int n = n0 + t * 16;
        float acc[8] = {0.f, 0.f, 0.f, 0.f, 0.f, 0.f, 0.f, 0.f};
        for (int mm = 0; mm < NN; ++mm) {
            float gv = gs[n][mm];
            us8 xv = *(const us8*)&xs[mm][dl * 8];
#pragma unroll
            for (int q = 0; q < 8; ++q) acc[q] += gv * bf2f(xv[q]);
        }
        us8 ov;
#pragma unroll
        for (int q = 0; q < 8; ++q) ov[q] = f2bf(acc[q]);
        *(us8*)(m.out + (size_t)(b * NN + n) * DD + d0 + dl * 8) = ov;
    }
}

// ---------------------------------------------------------------------------
// MFMA GEMM: out = epi(A1@W1t^T (+A2@W2t^T) + bias)   [M=4096, N=512, K=512]
// A row-major [m][k] bf16, Wt row-major [n][k] bf16.
// 128x128 tile, BK=32, 256 thr = 4 waves, wave = 64x64 quadrant (4x4 MFMA).
// LDS XOR swizzle: (row r, slot s) at byte r*64 + (s ^ ((r>>1)&3))*16.
// ---------------------------------------------------------------------------
struct GA {
    const unsigned short* A1; const unsigned short* W1;
    const unsigned short* A2; const unsigned short* W2;
    const float* bias;
    const unsigned short* gin1; const unsigned short* gin2;
    unsigned short* out;
};

template <bool DUAL, bool GATE>
__global__ __launch_bounds__(256) void mgemm_k(GA a0, GA a1) {
    GA g = (blockIdx.z == 0) ? a0 : a1;
    __shared__ __align__(16) unsigned short As[128 * 32];
    __shared__ __align__(16) unsigned short Bs[128 * 32];
    const int tid = threadIdx.x;
    const int lane = tid & 63;
    const int wave = tid >> 6;
    const int wr = wave & 1, wc = wave >> 1;
    const int bm = blockIdx.x * 128, bn = blockIdx.y * 128;

    f32x4 acc[4][4];
#pragma unroll
    for (int i = 0; i < 4; ++i)
#pragma unroll
        for (int j = 0; j < 4; ++j) {
            acc[i][j].x = 0.f; acc[i][j].y = 0.f; acc[i][j].z = 0.f; acc[i][j].w = 0.f;
        }

    // staging entries: e = tid + t*256 ; r = e>>2 ; s = (e&3) ^ ((r>>1)&3)
    const int r0 = tid >> 2,        s0 = (tid & 3) ^ ((r0 >> 1) & 3);
    const int r1 = (tid + 256) >> 2, s1 = (tid & 3) ^ ((r1 >> 1) & 3);
    unsigned short* ldsA0 = As + (size_t)(wave * 64) * 8;
    unsigned short* ldsA1 = As + (size_t)(256 + wave * 64) * 8;
    unsigned short* ldsB0 = Bs + (size_t)(wave * 64) * 8;
    unsigned short* ldsB1 = Bs + (size_t)(256 + wave * 64) * 8;

    // fragment LDS offsets (shorts)
    const int kq = lane >> 4;
    int aoff[4], boff[4];
#pragma unroll
    for (int i = 0; i < 4; ++i) {
        int m = wr * 64 + i * 16 + (lane & 15);
        aoff[i] = m * 32 + ((kq ^ ((m >> 1) & 3)) * 8);
        int n = wc * 64 + i * 16 + (lane & 15);
        boff[i] = n * 32 + ((kq ^ ((n >> 1) & 3)) * 8);
    }

    const int nsrc = DUAL ? 2 : 1;
    for (int src = 0; src < nsrc; ++src) {
        const unsigned short* A = src ? g.A2 : g.A1;
        const unsigned short* W = src ? g.W2 : g.W1;
        for (int k0 = 0; k0 < DD; k0 += 32) {
            g2l16(A + (size_t)(bm + r0) * DD + k0 + s0 * 8, ldsA0);
            g2l16(A + (size_t)(bm + r1) * DD + k0 + s1 * 8, ldsA1);
            g2l16(W + (size_t)(bn + r0) * DD + k0 + s0 * 8, ldsB0);
            g2l16(W + (size_t)(bn + r1) * DD + k0 + s1 * 8, ldsB1);
            __syncthreads();
            bf16x8 af[4], bfr[4];
#pragma unroll
            for (int i = 0; i < 4; ++i) {
                af[i] = *(const bf16x8*)(As + aoff[i]);
                bfr[i] = *(const bf16x8*)(Bs + boff[i]);
            }
#pragma unroll
            for (int i = 0; i < 4; ++i)
#pragma unroll
                for (int j = 0; j < 4; ++j)
                    acc[i][j] = __builtin_amdgcn_mfma_f32_16x16x32_bf16(af[i], bfr[j],
                                                                        acc[i][j], 0, 0, 0);
            __syncthreads();
        }
    }

    // epilogue: C/D layout col=lane&15, row=(lane>>4)*4+reg
#pragma unroll
    for (int i = 0; i < 4; ++i) {
        int row = bm + wr * 64 + i * 16 + (lane >> 4) * 4;
#pragma unroll
        for (int j = 0; j < 4; ++j) {
            int col = bn + wc * 64 + j * 16 + (lane & 15);
            float bv = g.bias[col];
#pragma unroll
            for (int rg = 0; rg < 4; ++rg) {
                float v = acc[i][j][rg] + bv;
                size_t idx = (size_t)(row + rg) * DD + col;
                if (GATE) {
                    float gg = 1.f / (1.f + __expf(-v));
                    float x1 = bf2f(g.gin1[idx]);
                    float x2 = bf2f(g.gin2[idx]);
                    g.out[idx] = f2bf(gg * x1 + (1.f - gg) * x2);
                } else {
                    g.out[idx] = f2bf(fmaxf(v, 0.f));
                }
            }
        }
    }
}

// ---------------------------------------------------------------------------
// Outputs
// ---------------------------------------------------------------------------
__global__ __launch_bounds__(256) void gnn_k(const float* __restrict__ enc,
                                             const unsigned short* __restrict__ node,
                                             const int* __restrict__ slot,
                                             float* __restrict__ out_gnn,
                                             float* __restrict__ partial) {
    int b = blockIdx.x;
    int s0 = blockIdx.y * 32;
    int t = threadIdx.x;
    float mx0 = -INFINITY, mx1 = -INFINITY;
    for (int s = s0; s < s0 + 32; ++s) {
        int n = slot[b * SS + s];
        size_t ebase = ((size_t)s * BB + b) * DD;
        float a0 = 0.f, a1 = 0.f;
        if (n >= 0) {
            size_t nbase = ((size_t)b * NN + n) * DD;
            a0 = bf2f(node[nbase + t]);
            a1 = bf2f(node[nbase + t + 256]);
        }
        float v0 = enc[ebase + t] + a0;
        float v1 = enc[ebase + t + 256] + a1;
        out_gnn[ebase + t] = v0;
        out_gnn[ebase + t + 256] = v1;
        mx0 = fmaxf(mx0, v0);
        mx1 = fmaxf(mx1, v1);
    }
    size_t pbase = ((size_t)b * 16 + blockIdx.y) * DD;
    partial[pbase + t] = mx0;
    partial[pbase + t + 256] = mx1;
}

__global__ void pmax_k(const float* __restrict__ partial, float* __restrict__ out_prob) {
    int i = blockIdx.x * 256 + threadIdx.x;
    if (i >= BB * DD) return;
    int b = i >> 9, d = i & 511;
    float m = -INFINITY;
    for (int c = 0; c < 16; ++c) m = fmaxf(m, partial[((size_t)b * 16 + c) * DD + d]);
    out_prob[i] = m;
}

__global__ void nemb_k(const float* __restrict__ num_enc,
                       const unsigned short* __restrict__ node,
                       float* __restrict__ out) {
    size_t i = ((size_t)blockIdx.x * 256 + threadIdx.x) * 4;
    float4 a = *(const float4*)(num_enc + i);
    ushort4 nb = *(const ushort4*)(node + i);
    float4 r;
    r.x = a.x + bf2f(nb.x);
    r.y = a.y + bf2f(nb.y);
    r.z = a.z + bf2f(nb.z);
    r.w = a.w + bf2f(nb.w);
    *(float4*)(out + i) = r;
}

// ---------------------------------------------------------------------------
// Host launch
// ---------------------------------------------------------------------------
extern "C" void kernel_launch(void* const* d_in, const int* in_sizes, int n_in,
                              void* d_out, int out_size, void* d_ws, size_t ws_size,
                              hipStream_t stream) {
    const float* enc     = (const float*)d_in[0];
    const float* num_enc = (const float*)d_in[1];
    const int*   pos     = (const int*)d_in[2];
    const int*   order   = (const int*)d_in[3];
    const float* w_n1a = (const float*)d_in[4];  const float* b_n1a = (const float*)d_in[5];
    const float* w_n1b = (const float*)d_in[6];  const float* b_n1b = (const float*)d_in[7];
    const float* w_n2a = (const float*)d_in[8];  const float* b_n2a = (const float*)d_in[9];
    const float* w_n2b = (const float*)d_in[10]; const float* b_n2b = (const float*)d_in[11];
    const float* w_g   = (const float*)d_in[12]; const float* b_g   = (const float*)d_in[13];
    const float* w_o   = (const float*)d_in[14]; const float* b_o   = (const float*)d_in[15];

    char* wp = (char*)d_ws;
    float* g_gt = (float*)wp;        wp += (size_t)BB * NN * NN * 4;
    float* g_lt = (float*)wp;        wp += (size_t)BB * NN * NN * 4;
    float* partial = (float*)wp;     wp += (size_t)BB * 16 * DD * 4;
    int* slot = (int*)wp;            wp += (size_t)BB * SS * 4;
    unsigned short* Wt = (unsigned short*)wp;    wp += (size_t)16 * DSQ * 2;
    unsigned short* node0 = (unsigned short*)wp; wp += (size_t)MM * DD * 2;
    unsigned short* nodeA = (unsigned short*)wp; wp += (size_t)MM * DD * 2;
    unsigned short* nodeB = (unsigned short*)wp; wp += (size_t)MM * DD * 2;
    unsigned short* ni1 = (unsigned short*)wp;   wp += (size_t)MM * DD * 2;
    unsigned short* ni2 = (unsigned short*)wp;   wp += (size_t)MM * DD * 2;
    unsigned short* tmp1 = (unsigned short*)wp;  wp += (size_t)MM * DD * 2;
    unsigned short* tmp2 = (unsigned short*)wp;  wp += (size_t)MM * DD * 2;

    float* out_gnn  = (float*)d_out;
    float* out_nemb = out_gnn + (size_t)SS * BB * DD;
    float* out_prob = out_nemb + (size_t)BB * NN * DD;

    // Setup
    adj_k<<<BB, 256, 0, stream>>>(order, g_gt, g_lt);
    slot_init_k<<<(BB * SS) / 256, 256, 0, stream>>>(slot);
    slot_scatter_k<<<(BB * NN) / 256, 256, 0, stream>>>(pos, slot);

    WS wsrc;
    const float* srcs[12] = {w_n1a, w_n1b, w_n2a, w_n2b, w_o, w_o + DSQ,
                             w_n1a + DSQ, w_n1b + DSQ, w_n2a + DSQ, w_n2b + DSQ,
                             w_o + 2 * DSQ, w_o + 3 * DSQ};
    int slots[12] = {0, 1, 2, 3, 6, 7, 8, 9, 10, 11, 14, 15};
    for (int i = 0; i < 12; ++i) { wsrc.s[i] = srcs[i]; wsrc.slot[i] = slots[i]; }
    wprep_k<<<dim3(12, 64), 256, 0, stream>>>(wsrc, Wt);
    cwg_k<<<dim3(2, 64), 256, 0, stream>>>(w_g, Wt);
    conv_k<<<(MM * DD) / 1024, 256, 0, stream>>>(num_enc, node0);

    dim3 ggrid(BB, 4, 2);
    dim3 pgrid(MM / 128, DD / 128, 2);
    dim3 sgrid(MM / 128, DD / 128, 1);

    const unsigned short* nodeIn = node0;
    for (int h = 0; h < HH; ++h) {
        unsigned short* nodeOut = (h == 0) ? nodeA : nodeB;
        const unsigned short* Wh = Wt + (size_t)h * 8 * DSQ;

        GM m0 = {g_gt, nodeIn, tmp1};
        GM m1 = {g_lt, nodeIn, tmp2};
        gmul_k<<<ggrid, 256, 0, stream>>>(m0, m1);

        GA ga0 = {tmp1, Wh + 0 * DSQ, nullptr, nullptr, b_n1a + h * DD, nullptr, nullptr, ni1};
        GA ga1 = {tmp2, Wh + 2 * DSQ, nullptr, nullptr, b_n2a + h * DD, nullptr, nullptr, ni2};
        mgemm_k<false, false><<<pgrid, 256, 0, stream>>>(ga0, ga1);

        GM m2 = {g_gt, ni1, tmp1};
        GM m3 = {g_lt, ni2, tmp2};
        gmul_k<<<ggrid, 256, 0, stream>>>(m2, m3);

        GA gb0 = {tmp1, Wh + 1 * DSQ, nullptr, nullptr, b_n1b + h * DD, nullptr, nullptr, ni1};
        GA gb1 = {tmp2, Wh + 3 * DSQ, nullptr, nullptr, b_n2b + h * DD, nullptr, nullptr, ni2};
        mgemm_k<false, false><<<pgrid, 256, 0, stream>>>(gb0, gb1);

        GA gg = {ni1, Wh + 4 * DSQ, ni2, Wh + 5 * DSQ, b_g + h * DD, ni1, ni2, tmp1};
        mgemm_k<true, true><<<sgrid, 256, 0, stream>>>(gg, gg);

        GA go = {nodeIn, Wh + 6 * DSQ, tmp1, Wh + 7 * DSQ, b_o + h * DD, nullptr, nullptr, nodeOut};
        mgemm_k<true, false><<<sgrid, 256, 0, stream>>>(go, go);

        nodeIn = nodeOut;
    }
    const unsigned short* nodeF = nodeIn;

    gnn_k<<<dim3(BB, 16), 256, 0, stream>>>(enc, nodeF, slot, out_gnn, partial);
    pmax_k<<<(BB * DD) / 256, 256, 0, stream>>>(partial, out_prob);
    nemb_k<<<(BB * NN * DD) / 1024, 256, 0, stream>>>(num_enc, nodeF, out_nemb);
}

// Round 3
// 433.657 us; speedup vs baseline: 2.2149x; 1.2039x over previous
//
#include <hip/hip_runtime.h>
#include <math.h>

// Problem constants
#define BB 128
#define SS 512
#define NN 32
#define DD 512
#define HH 2
#define MM (BB * NN)          // 4096 rows
#define DSQ (DD * DD)         // 262144

typedef short bf16x8 __attribute__((ext_vector_type(8)));
typedef float f32x4 __attribute__((ext_vector_type(4)));

__device__ __forceinline__ unsigned short f2bf(float f) {
    unsigned int u = __float_as_uint(f);
    u += 0x7fffu + ((u >> 16) & 1u);
    return (unsigned short)(u >> 16);
}
__device__ __forceinline__ float bf2f(unsigned short h) {
    return __uint_as_float(((unsigned int)h) << 16);
}
__device__ __forceinline__ void g2l16(const void* gp, void* lp) {
    __builtin_amdgcn_global_load_lds(
        (const __attribute__((address_space(1))) void*)gp,
        (__attribute__((address_space(3))) void*)lp, 16, 0, 0);
}

// ---------------------------------------------------------------------------
// adj + slot map fused: g_gt/g_lt [B,32,32] row-normalized; slot[b][s]
// ---------------------------------------------------------------------------
__global__ __launch_bounds__(256) void adj_k(const int* __restrict__ order,
                                             const int* __restrict__ pos,
                                             float* __restrict__ g_gt,
                                             float* __restrict__ g_lt,
                                             int* __restrict__ slot) {
    int b = blockIdx.x;
    __shared__ int ord[NN];
    __shared__ float sgt[NN][NN + 1];
    __shared__ float slt[NN][NN + 1];
    __shared__ float rs_gt[NN], rs_lt[NN];
    int tid = threadIdx.x;
    // slot init (barrier below orders these before the scatter at the end)
    slot[b * SS + tid] = -1;
    slot[b * SS + 256 + tid] = -1;
    if (tid < NN) ord[tid] = order[b * NN + tid];
    __syncthreads();
    for (int q = 0; q < 4; ++q) {
        int idx = tid + 256 * q;
        int n = idx >> 5, m = idx & 31;
        bool valid = (ord[n] > 0) && (ord[m] > 0) && (n != m);
        float eye = (n == m) ? 1.f : 0.f;
        bool gt = ord[n] > ord[m];
        sgt[n][m] = ((valid && gt) ? 1.f : 0.f) + eye;
        slt[n][m] = ((valid && !gt) ? 1.f : 0.f) + eye;
    }
    __syncthreads();
    if (tid < NN) {
        float s1 = 0.f, s2 = 0.f;
        for (int m = 0; m < NN; ++m) { s1 += sgt[tid][m]; s2 += slt[tid][m]; }
        rs_gt[tid] = s1; rs_lt[tid] = s2;
    }
    __syncthreads();
    for (int q = 0; q < 4; ++q) {
        int idx = tid + 256 * q;
        int n = idx >> 5, m = idx & 31;
        g_gt[b * 1024 + idx] = sgt[n][m] / rs_gt[n];
        g_lt[b * 1024 + idx] = slt[n][m] / rs_lt[n];
    }
    if (tid < NN) {
        int p = pos[b * NN + tid];
        if (p >= 0) slot[b * SS + p] = tid;
    }
}

// ---------------------------------------------------------------------------
// Weight prep (transpose + bf16) + gate-weight combine, one kernel.
// grid (14, 64): which<12 plain transpose; which 12,13 = combined gate W h=0,1
// ---------------------------------------------------------------------------
struct WSfull { const float* s[12]; int slot[12]; const float* w_g; };

__global__ __launch_bounds__(256) void wprep_k(WSfull w, unsigned short* __restrict__ Wt) {
    int which = blockIdx.x;
    int tile = blockIdx.y;
    int tr = (tile >> 3) * 64, tc = (tile & 7) * 64;
    __shared__ float c1[64][65];
    __shared__ float c2[64][65];
    int lc = threadIdx.x & 63, g4 = threadIdx.x >> 6;
    if (which < 12) {
        const float* src = w.s[which];
        unsigned short* dst = Wt + (size_t)w.slot[which] * DSQ;
        for (int i = 0; i < 16; ++i) {
            int lr = g4 * 16 + i;
            c1[lr][lc] = src[(size_t)(tr + lr) * DD + tc + lc];
        }
        __syncthreads();
        for (int i = 0; i < 16; ++i) {
            int lr = g4 * 16 + i;
            dst[(size_t)(tc + lr) * DD + tr + lc] = f2bf(c1[lc][lr]);
        }
    } else {
        int h = which - 12;
        const float* base = w.w_g + (size_t)h * 4 * DSQ;
        for (int i = 0; i < 16; ++i) {
            int lr = g4 * 16 + i;
            int k = tr + lr, n = tc + lc;
            float a  = base[(size_t)k * DD + n];
            float b2 = base[(size_t)(DD + k) * DD + n];
            float c  = base[(size_t)(2 * DD + k) * DD + n];
            float d4 = base[(size_t)(3 * DD + k) * DD + n];
            c1[lr][lc] = a + c + d4;
            c2[lr][lc] = b2 + c - d4;
        }
        __syncthreads();
        unsigned short* d1 = Wt + (size_t)(h * 8 + 4) * DSQ;
        unsigned short* d2 = Wt + (size_t)(h * 8 + 5) * DSQ;
        for (int i = 0; i < 16; ++i) {
            int lr = g4 * 16 + i;
            d1[(size_t)(tc + lr) * DD + tr + lc] = f2bf(c1[lc][lr]);
            d2[(size_t)(tc + lr) * DD + tr + lc] = f2bf(c2[lc][lr]);
        }
    }
}

// fp32 -> bf16 conversion (num_enc -> node0)
__global__ void conv_k(const float* __restrict__ x, unsigned short* __restrict__ o) {
    size_t i = ((size_t)blockIdx.x * 256 + threadIdx.x) * 4;
    float4 v = *(const float4*)(x + i);
    ushort4 r;
    r.x = f2bf(v.x); r.y = f2bf(v.y); r.z = f2bf(v.z); r.w = f2bf(v.w);
    *(ushort4*)(o + i) = r;
}

// ---------------------------------------------------------------------------
// MFMA GEMM, 64x64 tile, BK=64, 4 waves (each 32x32 via 2x2 MFMA 16x16x32).
//  MIX:  out = relu(g-mix(A@W^T) + bias)   (g applied post-GEMM, fp32)
//  GATE: gate = sigmoid(A1@W1+A2@W2+bias); out = gate*gin1+(1-gate)*gin2
//  else: out = relu(A@W^T (+A2@W2^T) + bias)
// LDS staging swizzle: row r (128 B), slot s at pos p = s ^ (r&7).
// ---------------------------------------------------------------------------
struct GA {
    const unsigned short* A1; const unsigned short* W1;
    const unsigned short* A2; const unsigned short* W2;
    const float* g; const float* bias;
    const unsigned short* gin1; const unsigned short* gin2;
    unsigned short* out;
};

template <bool MIX, bool DUAL, bool GATE>
__global__ __launch_bounds__(256) void mgemm_k(GA a0, GA a1) {
    GA g = (blockIdx.z == 0) ? a0 : a1;
    __shared__ __align__(16) unsigned short stag[8192];  // A [0,4096) B [4096,8192) shorts
    __shared__ float gsh[2048];                          // [2][32][32] fp32
    const int tid = threadIdx.x;
    const int lane = tid & 63;
    const int wave = tid >> 6;
    const int wr = wave & 1, wc = wave >> 1;
    const int bm = blockIdx.x * 64, bn = blockIdx.y * 64;

    if (MIX) {
        const float4* gsrc = (const float4*)(g.g + (size_t)(bm >> 5) * 1024);
        ((float4*)gsh)[tid] = gsrc[tid];
        ((float4*)gsh)[tid + 256] = gsrc[tid + 256];
    }

    f32x4 acc[2][2];
#pragma unroll
    for (int i = 0; i < 2; ++i)
#pragma unroll
        for (int j = 0; j < 2; ++j) {
            acc[i][j].x = 0.f; acc[i][j].y = 0.f; acc[i][j].z = 0.f; acc[i][j].w = 0.f;
        }

    // staging: entry e at LDS byte e*16; r=e>>3, pos=e&7 holds global slot s=pos^(r&7)
    const int r0 = tid >> 3,          s0 = (tid & 7) ^ (r0 & 7);
    const int r1 = (tid + 256) >> 3,  s1 = (tid & 7) ^ (r1 & 7);
    unsigned short* As = stag;
    unsigned short* Bs = stag + 4096;
    unsigned short* dA0 = As + wave * 512;
    unsigned short* dA1 = As + 2048 + wave * 512;
    unsigned short* dB0 = Bs + wave * 512;
    unsigned short* dB1 = Bs + 2048 + wave * 512;

    // fragment LDS offsets (shorts): [micro-k t][frag i]
    int aoff[2][2], boff[2][2];
#pragma unroll
    for (int t = 0; t < 2; ++t)
#pragma unroll
        for (int i = 0; i < 2; ++i) {
            int s = t * 4 + (lane >> 4);
            int p = s ^ (lane & 7);
            int m = wr * 32 + i * 16 + (lane & 15);
            aoff[t][i] = m * 64 + p * 8;
            int n = wc * 32 + i * 16 + (lane & 15);
            boff[t][i] = n * 64 + p * 8;
        }

    const int nsrc = DUAL ? 2 : 1;
    for (int src = 0; src < nsrc; ++src) {
        const unsigned short* A = src ? g.A2 : g.A1;
        const unsigned short* W = src ? g.W2 : g.W1;
        const unsigned short* Ab0 = A + (size_t)(bm + r0) * DD + s0 * 8;
        const unsigned short* Ab1 = A + (size_t)(bm + r1) * DD + s1 * 8;
        const unsigned short* Wb0 = W + (size_t)(bn + r0) * DD + s0 * 8;
        const unsigned short* Wb1 = W + (size_t)(bn + r1) * DD + s1 * 8;
        for (int k0 = 0; k0 < DD; k0 += 64) {
            g2l16(Ab0 + k0, dA0);
            g2l16(Ab1 + k0, dA1);
            g2l16(Wb0 + k0, dB0);
            g2l16(Wb1 + k0, dB1);
            __syncthreads();
            bf16x8 af[2][2], bf_[2][2];
#pragma unroll
            for (int t = 0; t < 2; ++t)
#pragma unroll
                for (int i = 0; i < 2; ++i) {
                    af[t][i]  = *(const bf16x8*)(As + aoff[t][i]);
                    bf_[t][i] = *(const bf16x8*)(Bs + boff[t][i]);
                }
#pragma unroll
            for (int t = 0; t < 2; ++t)
#pragma unroll
                for (int i = 0; i < 2; ++i)
#pragma unroll
                    for (int j = 0; j < 2; ++j)
                        acc[i][j] = __builtin_amdgcn_mfma_f32_16x16x32_bf16(
                            af[t][i], bf_[t][j], acc[i][j], 0, 0, 0);
            __syncthreads();
        }
    }

    if (!MIX) {
#pragma unroll
        for (int i = 0; i < 2; ++i) {
            int row = bm + wr * 32 + i * 16 + (lane >> 4) * 4;
#pragma unroll
            for (int j = 0; j < 2; ++j) {
                int col = bn + wc * 32 + j * 16 + (lane & 15);
                float bv = g.bias[col];
#pragma unroll
                for (int rg = 0; rg < 4; ++rg) {
                    float v = acc[i][j][rg] + bv;
                    size_t idx = (size_t)(row + rg) * DD + col;
                    if (GATE) {
                        float gg = 1.f / (1.f + __expf(-v));
                        float x1 = bf2f(g.gin1[idx]);
                        float x2 = bf2f(g.gin2[idx]);
                        g.out[idx] = f2bf(gg * x1 + (1.f - gg) * x2);
                    } else {
                        g.out[idx] = f2bf(fmaxf(v, 0.f));
                    }
                }
            }
        }
    } else {
        // stage raw C tile to LDS (fp32, 64x64 = 16 KB overlays staging)
        float* S = (float*)stag;
#pragma unroll
        for (int i = 0; i < 2; ++i) {
            int row = wr * 32 + i * 16 + (lane >> 4) * 4;
#pragma unroll
            for (int j = 0; j < 2; ++j) {
                int col = wc * 32 + j * 16 + (lane & 15);
#pragma unroll
                for (int rg = 0; rg < 4; ++rg) S[(row + rg) * 64 + col] = acc[i][j][rg];
            }
        }
        __syncthreads();
        // mix: out[n,d] = relu(sum_m g[bt][n][m] * S[bt*32+m][d] + bias[d])
#pragma unroll
        for (int t = 0; t < 4; ++t) {
            int task = t * 256 + tid;        // 1024 tasks: n(0..63) x dq(0..15)
            int n = task >> 4, dq = task & 15;
            int bt = n >> 5, nl = n & 31;
            float r0m = 0.f, r1m = 0.f, r2m = 0.f, r3m = 0.f;
            const float* gr = gsh + bt * 1024 + nl * 32;
            const float* Sb = S + bt * 32 * 64 + dq * 4;
#pragma unroll
            for (int m = 0; m < 32; ++m) {
                float gv = gr[m];
                f32x4 sv = *(const f32x4*)(Sb + m * 64);
                r0m += gv * sv.x; r1m += gv * sv.y; r2m += gv * sv.z; r3m += gv * sv.w;
            }
            float4 bv = *(const float4*)(g.bias + bn + dq * 4);
            ushort4 ov;
            ov.x = f2bf(fmaxf(r0m + bv.x, 0.f));
            ov.y = f2bf(fmaxf(r1m + bv.y, 0.f));
            ov.z = f2bf(fmaxf(r2m + bv.z, 0.f));
            ov.w = f2bf(fmaxf(r3m + bv.w, 0.f));
            *(ushort4*)(g.out + (size_t)(bm + n) * DD + bn + dq * 4) = ov;
        }
    }
}

// ---------------------------------------------------------------------------
// Outputs: gnn_info + partial max (y<16) and num_embedding (y==16)
// ---------------------------------------------------------------------------
__global__ __launch_bounds__(256) void gnn_k(const float* __restrict__ enc,
                                             const unsigned short* __restrict__ node,
                                             const int* __restrict__ slot,
                                             const float* __restrict__ num_enc,
                                             float* __restrict__ out_gnn,
                                             float* __restrict__ out_nemb,
                                             float* __restrict__ partial) {
    int b = blockIdx.x;
    int t = threadIdx.x;
    if (blockIdx.y == 16) {
        size_t base = (size_t)b * NN * DD;
        for (int q = 0; q < 16; ++q) {
            size_t i = base + (size_t)(q * 256 + t) * 4;
            float4 a = *(const float4*)(num_enc + i);
            ushort4 nb = *(const ushort4*)(node + i);
            float4 r;
            r.x = a.x + bf2f(nb.x);
            r.y = a.y + bf2f(nb.y);
            r.z = a.z + bf2f(nb.z);
            r.w = a.w + bf2f(nb.w);
            *(float4*)(out_nemb + i) = r;
        }
        return;
    }
    int s0 = blockIdx.y * 32;
    float mx0 = -INFINITY, mx1 = -INFINITY;
    for (int s = s0; s < s0 + 32; ++s) {
        int n = slot[b * SS + s];
        size_t ebase = ((size_t)s * BB + b) * DD;
        float a0 = 0.f, a1 = 0.f;
        if (n >= 0) {
            size_t nbase = ((size_t)b * NN + n) * DD;
            a0 = bf2f(node[nbase + t]);
            a1 = bf2f(node[nbase + t + 256]);
        }
        float v0 = enc[ebase + t] + a0;
        float v1 = enc[ebase + t + 256] + a1;
        out_gnn[ebase + t] = v0;
        out_gnn[ebase + t + 256] = v1;
        mx0 = fmaxf(mx0, v0);
        mx1 = fmaxf(mx1, v1);
    }
    size_t pbase = ((size_t)b * 16 + blockIdx.y) * DD;
    partial[pbase + t] = mx0;
    partial[pbase + t + 256] = mx1;
}

__global__ void pmax_k(const float* __restrict__ partial, float* __restrict__ out_prob) {
    int i = blockIdx.x * 256 + threadIdx.x;
    if (i >= BB * DD) return;
    int b = i >> 9, d = i & 511;
    float m = -INFINITY;
    for (int c = 0; c < 16; ++c) m = fmaxf(m, partial[((size_t)b * 16 + c) * DD + d]);
    out_prob[i] = m;
}

// ---------------------------------------------------------------------------
// Host launch
// ---------------------------------------------------------------------------
extern "C" void kernel_launch(void* const* d_in, const int* in_sizes, int n_in,
                              void* d_out, int out_size, void* d_ws, size_t ws_size,
                              hipStream_t stream) {
    const float* enc     = (const float*)d_in[0];
    const float* num_enc = (const float*)d_in[1];
    const int*   pos     = (const int*)d_in[2];
    const int*   order   = (const int*)d_in[3];
    const float* w_n1a = (const float*)d_in[4];  const float* b_n1a = (const float*)d_in[5];
    const float* w_n1b = (const float*)d_in[6];  const float* b_n1b = (const float*)d_in[7];
    const float* w_n2a = (const float*)d_in[8];  const float* b_n2a = (const float*)d_in[9];
    const float* w_n2b = (const float*)d_in[10]; const float* b_n2b = (const float*)d_in[11];
    const float* w_g   = (const float*)d_in[12]; const float* b_g   = (const float*)d_in[13];
    const float* w_o   = (const float*)d_in[14]; const float* b_o   = (const float*)d_in[15];

    char* wp = (char*)d_ws;
    float* g_gt = (float*)wp;        wp += (size_t)BB * NN * NN * 4;
    float* g_lt = (float*)wp;        wp += (size_t)BB * NN * NN * 4;
    float* partial = (float*)wp;     wp += (size_t)BB * 16 * DD * 4;
    int* slot = (int*)wp;            wp += (size_t)BB * SS * 4;
    unsigned short* Wt = (unsigned short*)wp;    wp += (size_t)16 * DSQ * 2;
    unsigned short* node0 = (unsigned short*)wp; wp += (size_t)MM * DD * 2;
    unsigned short* nodeA = (unsigned short*)wp; wp += (size_t)MM * DD * 2;
    unsigned short* nodeB = (unsigned short*)wp; wp += (size_t)MM * DD * 2;
    unsigned short* ni1 = (unsigned short*)wp;   wp += (size_t)MM * DD * 2;
    unsigned short* ni2 = (unsigned short*)wp;   wp += (size_t)MM * DD * 2;
    unsigned short* t1 = (unsigned short*)wp;    wp += (size_t)MM * DD * 2;
    unsigned short* t2 = (unsigned short*)wp;    wp += (size_t)MM * DD * 2;

    float* out_gnn  = (float*)d_out;
    float* out_nemb = out_gnn + (size_t)SS * BB * DD;
    float* out_prob = out_nemb + (size_t)BB * NN * DD;

    // Setup (3 dispatches)
    adj_k<<<BB, 256, 0, stream>>>(order, pos, g_gt, g_lt, slot);

    WSfull wsrc;
    const float* srcs[12] = {w_n1a, w_n1b, w_n2a, w_n2b, w_o, w_o + DSQ,
                             w_n1a + DSQ, w_n1b + DSQ, w_n2a + DSQ, w_n2b + DSQ,
                             w_o + 2 * DSQ, w_o + 3 * DSQ};
    int slots[12] = {0, 1, 2, 3, 6, 7, 8, 9, 10, 11, 14, 15};
    for (int i = 0; i < 12; ++i) { wsrc.s[i] = srcs[i]; wsrc.slot[i] = slots[i]; }
    wsrc.w_g = w_g;
    wprep_k<<<dim3(14, 64), 256, 0, stream>>>(wsrc, Wt);
    conv_k<<<(MM * DD) / 1024, 256, 0, stream>>>(num_enc, node0);

    dim3 dgrid(MM / 64, DD / 64, 2);   // 64x8x2 = 1024 blocks
    dim3 sgrid(MM / 64, DD / 64, 1);   // 512 blocks

    const unsigned short* nodeIn = node0;
    for (int h = 0; h < HH; ++h) {
        unsigned short* nodeOut = (h == 0) ? nodeA : nodeB;
        const unsigned short* Wh = Wt + (size_t)h * 8 * DSQ;

        // stage A: ni1 = relu(g_gt-mix(x@W1a)+b); ni2 = relu(g_lt-mix(x@W2a)+b)
        GA sa0 = {nodeIn, Wh + 0 * DSQ, nullptr, nullptr, g_gt, b_n1a + h * DD,
                  nullptr, nullptr, ni1};
        GA sa1 = {nodeIn, Wh + 2 * DSQ, nullptr, nullptr, g_lt, b_n2a + h * DD,
                  nullptr, nullptr, ni2};
        mgemm_k<true, false, false><<<dgrid, 256, 0, stream>>>(sa0, sa1);

        // stage B: t1 = relu(g_gt-mix(ni1@W1b)+b); t2 = relu(g_lt-mix(ni2@W2b)+b)
        GA sb0 = {ni1, Wh + 1 * DSQ, nullptr, nullptr, g_gt, b_n1b + h * DD,
                  nullptr, nullptr, t1};
        GA sb1 = {ni2, Wh + 3 * DSQ, nullptr, nullptr, g_lt, b_n2b + h * DD,
                  nullptr, nullptr, t2};
        mgemm_k<true, false, false><<<dgrid, 256, 0, stream>>>(sb0, sb1);

        // gate: info = gate*t1 + (1-gate)*t2  -> ni1 (reused as info buffer)
        GA gg = {t1, Wh + 4 * DSQ, t2, Wh + 5 * DSQ, nullptr, b_g + h * DD, t1, t2, ni1};
        mgemm_k<false, true, true><<<sgrid, 256, 0, stream>>>(gg, gg);

        // out: node = relu(x@Wo_a + info@Wo_b + b)
        GA go = {nodeIn, Wh + 6 * DSQ, ni1, Wh + 7 * DSQ, nullptr, b_o + h * DD,
                 nullptr, nullptr, nodeOut};
        mgemm_k<false, true, false><<<sgrid, 256, 0, stream>>>(go, go);

        nodeIn = nodeOut;
    }
    const unsigned short* nodeF = nodeIn;

    // Outputs (2 dispatches)
    gnn_k<<<dim3(BB, 17), 256, 0, stream>>>(enc, nodeF, slot, num_enc,
                                            out_gnn, out_nemb, partial);
    pmax_k<<<(BB * DD) / 256, 256, 0, stream>>>(partial, out_prob);
}